// Round 1
// baseline (3003.033 us; speedup 1.0000x reference)
//
#include <hip/hip_runtime.h>
#include <math.h>

#define BN_EPS 1e-5f

// Problem constants
// N=32, C=64, O=64, T=1024, V=25, K=9, S=3

// Workspace layout (float offsets)
#define WS_AWP 0u           // Aw padded [3][25][32] = 2400
#define WS_WGT 2400u        // wgT [3][64][64] = 12288
#define WS_C1A 14688u       // [64]
#define WS_C1B 14752u
#define WS_C2A 14816u
#define WS_C2B 14880u
#define WS_Y   16384u       // y (N,C,T,V) = 52428800 floats

__device__ __forceinline__ void fma4(float4& a, float s, const float4& b) {
    a.x = fmaf(s, b.x, a.x);
    a.y = fmaf(s, b.y, a.y);
    a.z = fmaf(s, b.z, a.z);
    a.w = fmaf(s, b.w, a.w);
}

// ---------------- prep: fold BN constants, Aw = A*attn (padded), wg transpose ----------------
__global__ void prep_kernel(const float* __restrict__ A, const float* __restrict__ attn,
                            const float* __restrict__ wg, const float* __restrict__ bg,
                            const float* __restrict__ g1, const float* __restrict__ b1,
                            const float* __restrict__ m1, const float* __restrict__ v1,
                            const float* __restrict__ bt,
                            const float* __restrict__ g2, const float* __restrict__ b2,
                            const float* __restrict__ m2, const float* __restrict__ v2,
                            float* __restrict__ ws) {
    const int tid = threadIdx.x;
    float* awp = ws + WS_AWP;
    float* wgT = ws + WS_WGT;
    // Aw padded to [3][25][32] with zeros in v=25..31
    for (int idx = tid; idx < 3 * 25 * 32; idx += 256) {
        int s = idx / (25 * 32), r = idx % (25 * 32), w = r / 32, v = r % 32;
        awp[idx] = (v < 25) ? A[(s * 25 + w) * 25 + v] * attn[(s * 25 + w) * 25 + v] : 0.f;
    }
    // wgT[s][c][o] = wg[s][o][c]
    for (int idx = tid; idx < 3 * 64 * 64; idx += 256) {
        int s = idx / 4096, r = idx % 4096, c = r / 64, o = r % 64;
        wgT[idx] = wg[(s * 64 + o) * 64 + c];
    }
    if (tid < 64) {
        int o = tid;
        float inv1 = g1[o] * rsqrtf(v1[o] + BN_EPS);
        float bgsum = bg[o] + bg[64 + o] + bg[128 + o];
        ws[WS_C1A + o] = inv1;
        ws[WS_C1B + o] = bgsum * inv1 + b1[o] - m1[o] * inv1;
        float inv2 = g2[o] * rsqrtf(v2[o] + BN_EPS);
        ws[WS_C2A + o] = inv2;
        ws[WS_C2B + o] = bt[o] * inv2 + b2[o] - m2[o] * inv2;
    }
}

// ---------------- K1: graph conv + BN1 + residual + relu -> y(ws) ----------------
// One block per (n,t). h[o,v] = sum_s sum_c wgT[s][c][o] * agg[s][c][v],
// agg[s][c][v] = sum_w x[n,c,t,w] * Aw[s][w][v].
__global__ __launch_bounds__(256) void gcn_kernel(const float* __restrict__ x,
                                                  float* __restrict__ ws) {
    __shared__ float smem[10144];
    float* xs   = smem;          // [64][25] = 1600
    float* awl  = smem + 1600;   // [3][25][32] = 2400
    float* aggs = smem + 4000;   // [3][64][32] = 6144

    const int tid = threadIdx.x;
    const int bx = blockIdx.x;
    const int n = bx >> 10, t = bx & 1023;
    const float* awp = ws + WS_AWP;
    const float* wgT = ws + WS_WGT;
    float* yws = ws + WS_Y;

    for (int idx = tid; idx < 1600; idx += 256) {
        int c = idx / 25, v = idx % 25;
        xs[idx] = x[((size_t)(n * 64 + c) * 1024 + t) * 25 + v];
    }
    for (int idx = tid; idx < 2400; idx += 256) awl[idx] = awp[idx];
    __syncthreads();

    // Phase A: aggs[s][c][v], float4 over v (q = v/4, 8 quads incl. zero pad)
    const float4* aw4 = (const float4*)awl;
    float4* agg4 = (float4*)aggs;
    for (int idx = tid; idx < 1536; idx += 256) {
        int s = idx >> 9, r = idx & 511, c = r >> 3, q = r & 7;
        float4 acc = make_float4(0.f, 0.f, 0.f, 0.f);
#pragma unroll
        for (int w = 0; w < 25; ++w) {
            float xv = xs[c * 25 + w];
            fma4(acc, xv, aw4[(s * 25 + w) * 8 + q]);
        }
        agg4[(s * 64 + c) * 8 + q] = acc;
    }
    __syncthreads();

    // Phase B: each thread: 4 o's (othr*4..+3) x 8 v's (vq*8..+7), K split 4 ways (part)
    const int othr = tid & 15, vq = (tid >> 4) & 3, part = tid >> 6;
    float4 acc[4][2];
#pragma unroll
    for (int j = 0; j < 4; ++j) { acc[j][0] = make_float4(0,0,0,0); acc[j][1] = make_float4(0,0,0,0); }

    const float4* wgT4 = (const float4*)wgT;
#pragma unroll
    for (int s = 0; s < 3; ++s) {
        for (int ci = 0; ci < 16; ++ci) {
            int c = part * 16 + ci;
            int sc = s * 64 + c;
            float4 w4 = wgT4[sc * 16 + othr];
            float4 a = agg4[sc * 8 + vq * 2];
            float4 b = agg4[sc * 8 + vq * 2 + 1];
            fma4(acc[0][0], w4.x, a); fma4(acc[0][1], w4.x, b);
            fma4(acc[1][0], w4.y, a); fma4(acc[1][1], w4.y, b);
            fma4(acc[2][0], w4.z, a); fma4(acc[2][1], w4.z, b);
            fma4(acc[3][0], w4.w, a); fma4(acc[3][1], w4.w, b);
        }
    }
    __syncthreads();
    // reduction over the 4 K-parts via LDS (reuse smem; aggs reads are done)
    float* red = smem;  // [4][2048]
#pragma unroll
    for (int j = 0; j < 4; ++j) {
        float4* r4 = (float4*)(red + part * 2048 + (othr * 4 + j) * 32 + vq * 8);
        r4[0] = acc[j][0];
        r4[1] = acc[j][1];
    }
    __syncthreads();
    const float* c1a = ws + WS_C1A;
    const float* c1b = ws + WS_C1B;
    for (int f = tid; f < 2048; f += 256) {
        int o = f >> 5, v = f & 31;
        if (v < 25) {
            float sum = red[f] + red[2048 + f] + red[4096 + f] + red[6144 + f];
            size_t gi = ((size_t)(n * 64 + o) * 1024 + t) * 25 + v;
            float val = fmaf(sum, c1a[o], c1b[o]) + x[gi];
            yws[gi] = fmaxf(val, 0.f);
        }
    }
}

// ---------------- K2: temporal conv(9,1) + BN2 + residual + relu -> out ----------------
// Block per (n, 16-t chunk), covers all 64 o. Thread: oh=tid>>4 (4 o's), tl=tid&15 (1 t).
__global__ __launch_bounds__(256) void tcn_kernel(const float* __restrict__ x,
                                                  const float* __restrict__ wt,
                                                  float* __restrict__ ws,
                                                  float* __restrict__ out) {
    __shared__ float ych[16 * 24 * 28];  // i-chunk 16 x (16+8 halo t) x padded v
    const int tid = threadIdx.x;
    const int bx = blockIdx.x;
    const int n = bx >> 6, tc = bx & 63;
    const int t0 = tc * 16;
    const int oh = tid >> 4, tl = tid & 15;
    const float* yws = ws + WS_Y;

    float4 acc[4][7];
#pragma unroll
    for (int j = 0; j < 4; ++j)
#pragma unroll
        for (int q = 0; q < 7; ++q) acc[j][q] = make_float4(0.f, 0.f, 0.f, 0.f);

    for (int ic = 0; ic < 4; ++ic) {
        __syncthreads();
        for (int idx = tid; idx < 16 * 24 * 28; idx += 256) {
            int ii = idx / 672, r = idx % 672, tt = r / 28, v = r % 28;
            int gt = t0 - 4 + tt;
            float val = 0.f;
            if (v < 25 && gt >= 0 && gt < 1024)
                val = yws[((size_t)(n * 64 + ic * 16 + ii) * 1024 + gt) * 25 + v];
            ych[idx] = val;
        }
        __syncthreads();

        for (int il = 0; il < 16; ++il) {
            float w[4][9];
#pragma unroll
            for (int j = 0; j < 4; ++j)
#pragma unroll
                for (int k = 0; k < 9; ++k)
                    w[j][k] = wt[((size_t)(oh * 4 + j) * 64 + ic * 16 + il) * 9 + k];
#pragma unroll
            for (int k = 0; k < 9; ++k) {
                int row = tl + k;
                const float4* y4 = (const float4*)(ych + (il * 24 + row) * 28);
                float4 yv[7];
#pragma unroll
                for (int q = 0; q < 7; ++q) yv[q] = y4[q];
#pragma unroll
                for (int j = 0; j < 4; ++j) {
                    float wk = w[j][k];
#pragma unroll
                    for (int q = 0; q < 7; ++q) fma4(acc[j][q], wk, yv[q]);
                }
            }
        }
    }

    const float* c2a = ws + WS_C2A;
    const float* c2b = ws + WS_C2B;
    const int t = t0 + tl;
#pragma unroll
    for (int j = 0; j < 4; ++j) {
        int o = oh * 4 + j;
        float sa = c2a[o], sb = c2b[o];
#pragma unroll
        for (int q = 0; q < 7; ++q) {
            float comp[4] = {acc[j][q].x, acc[j][q].y, acc[j][q].z, acc[j][q].w};
#pragma unroll
            for (int e = 0; e < 4; ++e) {
                int v = q * 4 + e;
                if (v < 25) {
                    size_t gi = ((size_t)(n * 64 + o) * 1024 + t) * 25 + v;
                    out[gi] = fmaxf(fmaf(comp[e], sa, sb) + x[gi], 0.f);
                }
            }
        }
    }
}

extern "C" void kernel_launch(void* const* d_in, const int* in_sizes, int n_in,
                              void* d_out, int out_size, void* d_ws, size_t ws_size,
                              hipStream_t stream) {
    const float* x    = (const float*)d_in[0];
    const float* A    = (const float*)d_in[1];
    const float* attn = (const float*)d_in[2];
    const float* wg   = (const float*)d_in[3];
    const float* bg   = (const float*)d_in[4];
    const float* g1   = (const float*)d_in[5];
    const float* b1   = (const float*)d_in[6];
    const float* m1   = (const float*)d_in[7];
    const float* v1   = (const float*)d_in[8];
    const float* wt   = (const float*)d_in[9];
    const float* bt   = (const float*)d_in[10];
    const float* g2   = (const float*)d_in[11];
    const float* b2   = (const float*)d_in[12];
    const float* m2   = (const float*)d_in[13];
    const float* v2   = (const float*)d_in[14];
    float* ws  = (float*)d_ws;
    float* out = (float*)d_out;

    hipLaunchKernelGGL(prep_kernel, dim3(1), dim3(256), 0, stream,
                       A, attn, wg, bg, g1, b1, m1, v1, bt, g2, b2, m2, v2, ws);
    hipLaunchKernelGGL(gcn_kernel, dim3(32 * 1024), dim3(256), 0, stream, x, ws);
    hipLaunchKernelGGL(tcn_kernel, dim3(32 * 64), dim3(256), 0, stream, x, wt, ws, out);
}

// Round 3
// 760.198 us; speedup vs baseline: 3.9503x; 3.9503x over previous
//
#include <hip/hip_runtime.h>
#include <math.h>
#include <stdint.h>

#define BN_EPS 1e-5f

typedef unsigned short u16;
typedef unsigned int u32;
typedef __attribute__((ext_vector_type(8))) short short8;
typedef __attribute__((ext_vector_type(4))) float f32x4;

// N=32, C=O=64, T=1024, V=25, K=9, S=3
// ws layout (bytes):
#define OFF_YCL 0u            // y channel-last bf16 [n][t*25+v][64c]  : 104857600 B
#define OFF_AWP 104857600u    // AwT frags [3][2][64][8] u16           : 6144 B
#define OFF_WGP 104863744u    // wg  frags [3][2][4][64][8] u16        : 24576 B
#define OFF_WTP 104888320u    // wt  frags [18][4][64][8] u16          : 73728 B
#define OFF_C1A 104962048u
#define OFF_C1B 104962304u
#define OFF_C2A 104962560u
#define OFF_C2B 104962816u

__device__ __forceinline__ u16 f2bf(float f) {
    u32 u = __float_as_uint(f);
    u = (u + 0x7FFFu + ((u >> 16) & 1u)) >> 16;
    return (u16)u;
}
__device__ __forceinline__ float bf2f(u16 h) { return __uint_as_float(((u32)h) << 16); }

#define MFMA16(a, b, c) __builtin_amdgcn_mfma_f32_16x16x32_bf16((a), (b), (c), 0, 0, 0)

// ---------------- prep: BN folding + fragment pre-packing ----------------
__global__ void prep_kernel(const float* __restrict__ A, const float* __restrict__ attn,
                            const float* __restrict__ wg, const float* __restrict__ bg,
                            const float* __restrict__ g1, const float* __restrict__ b1,
                            const float* __restrict__ m1, const float* __restrict__ v1,
                            const float* __restrict__ wt, const float* __restrict__ bt,
                            const float* __restrict__ g2, const float* __restrict__ b2,
                            const float* __restrict__ m2, const float* __restrict__ v2,
                            char* __restrict__ ws) {
    const int tid = threadIdx.x;
    u16* awp = (u16*)(ws + OFF_AWP);
    u16* wgp = (u16*)(ws + OFF_WGP);
    u16* wtp = (u16*)(ws + OFF_WTP);
    float* c1a = (float*)(ws + OFF_C1A);
    float* c1b = (float*)(ws + OFF_C1B);
    float* c2a = (float*)(ws + OFF_C2A);
    float* c2b = (float*)(ws + OFF_C2B);

    // AwT A-frags: [s][mf][lane][j]; A[m=v][k=w] = A*attn [w][v], zero-padded
    for (int i = tid; i < 3072; i += 512) {
        int j = i & 7, lane = (i >> 3) & 63, mf = (i >> 9) & 1, s = i >> 10;
        int v = mf * 16 + (lane & 15), w = (lane >> 4) * 8 + j;
        float val = 0.f;
        if (v < 25 && w < 25) val = A[(s * 25 + w) * 25 + v] * attn[(s * 25 + w) * 25 + v];
        awp[i] = f2bf(val);
    }
    // wg B-frags: [s][ks][ot][lane][j]; B[k=c][n=o] = wg[s][o][c]
    for (int i = tid; i < 12288; i += 512) {
        int j = i & 7, lane = (i >> 3) & 63, ot = (i >> 9) & 3, ks = (i >> 11) & 1, s = i >> 12;
        int c = ks * 32 + (lane >> 4) * 8 + j, o = ot * 16 + (lane & 15);
        wgp[i] = f2bf(wg[(s * 64 + o) * 64 + c]);
    }
    // wt B-frags: [ks][ot][lane][j]; kappa = tap*64 + c (tap-major K=576)
    for (int i = tid; i < 36864; i += 512) {
        int j = i & 7, lane = (i >> 3) & 63, ot = (i >> 9) & 3, ks = i >> 11;
        int kk = ks * 32 + (lane >> 4) * 8 + j;
        int tap = kk >> 6, c = kk & 63, o = ot * 16 + (lane & 15);
        wtp[i] = f2bf(wt[(o * 64 + c) * 9 + tap]);
    }
    if (tid < 64) {
        int o = tid;
        float inv1 = g1[o] * rsqrtf(v1[o] + BN_EPS);
        float bgsum = bg[o] + bg[64 + o] + bg[128 + o];
        c1a[o] = inv1;
        c1b[o] = bgsum * inv1 + b1[o] - m1[o] * inv1;
        float inv2 = g2[o] * rsqrtf(v2[o] + BN_EPS);
        c2a[o] = inv2;
        c2b[o] = bt[o] * inv2 + b2[o] - m2[o] * inv2;
    }
}

// ---------------- K1: graph conv (MFMA) + BN1 + residual + relu -> ycl ----------------
// Block: (n, 16-t tile) = 400 output cols, 8 waves.
__global__ __launch_bounds__(512, 2) void gcn_kernel(const float* __restrict__ x,
                                                     char* __restrict__ ws) {
    __shared__ u16 xwl[16 * 64 * 32];  // x tile [t][c][w32] bf16, swz ^((c&3)<<3)  65536 B
    __shared__ u16 aggL[400 * 64];     // agg [row=tv][c] bf16, swz ^((row&7)<<3)   51200 B
    const u16* awp = (const u16*)(ws + OFF_AWP);
    const u16* wgp = (const u16*)(ws + OFF_WGP);
    const float* c1a = (const float*)(ws + OFF_C1A);
    const float* c1b = (const float*)(ws + OFF_C1B);
    u16* ycl = (u16*)(ws + OFF_YCL);

    const int tid = threadIdx.x;
    const int lane = tid & 63;
    const int wv = tid >> 6;
    const int n = blockIdx.y, tb = blockIdx.x;
    const int t0 = tb * 16;

    // AwT A-fragments (6) into regs
    short8 a1[6];
#pragma unroll
    for (int i = 0; i < 6; ++i) a1[i] = *(const short8*)(awp + (i * 64 + lane) * 8);

    // BN consts per o-frag
    float sa[4], sb[4];
#pragma unroll
    for (int ot = 0; ot < 4; ++ot) {
        int o = ot * 16 + (lane & 15);
        sa[ot] = c1a[o];
        sb[ot] = c1b[o];
    }

    // stage x -> xwl (bf16, w-contiguous rows of 32, swizzled); pad w=25..31 with 0
    const size_t xbase = (size_t)n * 64 * 1024 * 25;
    for (int e = tid; e < 25600; e += 512) {
        int t = e / 1600, rem = e - t * 1600;
        int c = rem / 25, v = rem - c * 25;
        float xv = x[xbase + ((size_t)c * 1024 + (t0 + t)) * 25 + v];
        xwl[((t * 64 + c) * 32 + v) ^ ((c & 3) << 3)] = f2bf(xv);
    }
    for (int e = tid; e < 16 * 64 * 7; e += 512) {
        int t = e / 448, rem = e - t * 448;
        int c = rem / 7, v = 25 + (rem - c * 7);
        xwl[((t * 64 + c) * 32 + v) ^ ((c & 3) << 3)] = 0;
    }
    __syncthreads();

    f32x4 acc[4][4];
#pragma unroll
    for (int i = 0; i < 4; ++i)
#pragma unroll
        for (int j = 0; j < 4; ++j) acc[i][j] = {0.f, 0.f, 0.f, 0.f};

    const int mfl[4] = {wv, wv + 8, wv + 16, 24};

#pragma unroll
    for (int s = 0; s < 3; ++s) {
        // ---- MFMA-1: agg_s[v,c] per t (wave owns t = 2wv, 2wv+1) ----
#pragma unroll
        for (int i = 0; i < 2; ++i) {
            const int t = wv * 2 + i;
            f32x4 d[2][4];
#pragma unroll
            for (int mf = 0; mf < 2; ++mf)
#pragma unroll
                for (int nf = 0; nf < 4; ++nf) d[mf][nf] = {0.f, 0.f, 0.f, 0.f};
#pragma unroll
            for (int nf = 0; nf < 4; ++nf) {
                int c = nf * 16 + (lane & 15);
                int w0 = (lane >> 4) * 8;
                short8 b = *(const short8*)&xwl[((t * 64 + c) * 32 + w0) ^ ((c & 3) << 3)];
                d[0][nf] = MFMA16(a1[s * 2 + 0], b, d[0][nf]);
                d[1][nf] = MFMA16(a1[s * 2 + 1], b, d[1][nf]);
            }
#pragma unroll
            for (int mf = 0; mf < 2; ++mf)
#pragma unroll
                for (int nf = 0; nf < 4; ++nf)
#pragma unroll
                    for (int r = 0; r < 4; ++r) {
                        int v = mf * 16 + (lane >> 4) * 4 + r;
                        if (v < 25) {
                            int row = t * 25 + v;
                            int c = nf * 16 + (lane & 15);
                            aggL[(row * 64 + c) ^ ((row & 7) << 3)] = f2bf(d[mf][nf][r]);
                        }
                    }
        }
        __syncthreads();
        // ---- MFMA-2: h += Wg_s . agg_s  (K=64) ----
        short8 bw[2][4];
#pragma unroll
        for (int ks = 0; ks < 2; ++ks)
#pragma unroll
            for (int ot = 0; ot < 4; ++ot)
                bw[ks][ot] = *(const short8*)(wgp + (((s * 2 + ks) * 4 + ot) * 64 + lane) * 8);
#pragma unroll
        for (int ks = 0; ks < 2; ++ks)
#pragma unroll
            for (int p = 0; p < 4; ++p) {
                int col = mfl[p] * 16 + (lane & 15);
                int c0 = ks * 32 + (lane >> 4) * 8;
                short8 a = *(const short8*)&aggL[(col * 64 + c0) ^ ((col & 7) << 3)];
#pragma unroll
                for (int ot = 0; ot < 4; ++ot) acc[p][ot] = MFMA16(a, bw[ks][ot], acc[p][ot]);
            }
        __syncthreads();
    }

    // epilogue: BN1 + residual(x from xwl) + relu -> trbuf (reuse aggL)
#pragma unroll
    for (int p = 0; p < 4; ++p) {
        if (p < 3 || wv == 0) {
            int mf = mfl[p];
#pragma unroll
            for (int ot = 0; ot < 4; ++ot) {
                int o = ot * 16 + (lane & 15);
#pragma unroll
                for (int r = 0; r < 4; ++r) {
                    int row = mf * 16 + (lane >> 4) * 4 + r;
                    int tl = row / 25, v = row - tl * 25;
                    float xr = bf2f(xwl[((tl * 64 + o) * 32 + v) ^ ((o & 3) << 3)]);
                    float val = fmaf(acc[p][ot][r], sa[ot], sb[ot]) + xr;
                    val = fmaxf(val, 0.f);
                    aggL[(row * 64 + o) ^ ((row & 7) << 3)] = f2bf(val);
                }
            }
        }
    }
    __syncthreads();
    // copy trbuf -> global ycl (16B chunks, coalesced)
    const size_t ybase = ((size_t)n * 25600 + (size_t)t0 * 25) * 64;
    for (int idx = tid; idx < 3200; idx += 512) {
        int row = idx >> 3, cg = idx & 7;
        short8 vv = *(const short8*)&aggL[(row * 64 + cg * 8) ^ ((row & 7) << 3)];
        *(short8*)(ycl + ybase + row * 64 + cg * 8) = vv;
    }
}

// ---------------- K2: temporal conv (MFMA, K=576) + BN2 + residual + relu -> out ----------------
// Block: (n, 512-col tile), 8 waves x (64 cols x 64 o). Halo +-100 cols staged.
__global__ __launch_bounds__(512, 2) void tcn_kernel(const float* __restrict__ x,
                                                     char* __restrict__ ws,
                                                     float* __restrict__ out) {
    __shared__ u16 ytile[712 * 64];  // [st][c] bf16, swz ^((st&7)<<3)  91136 B
    const u16* ycl = (const u16*)(ws + OFF_YCL);
    const u16* wtp = (const u16*)(ws + OFF_WTP);
    const float* c2a = (const float*)(ws + OFF_C2A);
    const float* c2b = (const float*)(ws + OFF_C2B);

    const int tid = threadIdx.x, lane = tid & 63, wv = tid >> 6;
    const int n = blockIdx.y, cb = blockIdx.x;
    const int col0 = cb * 512;
    const u16* yn = ycl + (size_t)n * 25600 * 64;

    // prefetch B chunk 0 (ks 0..2) while staging
    short8 B0[3][4], B1[3][4];
#pragma unroll
    for (int k3 = 0; k3 < 3; ++k3)
#pragma unroll
        for (int ot = 0; ot < 4; ++ot)
            B0[k3][ot] = *(const short8*)(wtp + ((k3 * 4 + ot) * 64 + lane) * 8);

    float sa[4], sb[4];
#pragma unroll
    for (int ot = 0; ot < 4; ++ot) {
        int o = ot * 16 + (lane & 15);
        sa[ot] = c2a[o];
        sb[ot] = c2b[o];
    }

    // stage y tile with halo, zero OOB
    for (int idx = tid; idx < 5696; idx += 512) {
        int st = idx >> 3, cg = idx & 7;
        int gcol = col0 - 100 + st;
        short8 v = {0, 0, 0, 0, 0, 0, 0, 0};
        if (gcol >= 0 && gcol < 25600) v = *(const short8*)(yn + (size_t)gcol * 64 + cg * 8);
        *(short8*)&ytile[(st * 64 + cg * 8) ^ ((st & 7) << 3)] = v;
    }
    __syncthreads();

    f32x4 acc[4][4];
#pragma unroll
    for (int i = 0; i < 4; ++i)
#pragma unroll
        for (int j = 0; j < 4; ++j) acc[i][j] = {0.f, 0.f, 0.f, 0.f};

    const int st0 = wv * 64 + (lane & 15);
    const int c0g = (lane >> 4) * 8;

#pragma unroll
    for (int cc = 0; cc < 6; ++cc) {
        if (cc < 5) {
            auto& Bn = (cc & 1) ? B0 : B1;
#pragma unroll
            for (int k3 = 0; k3 < 3; ++k3)
#pragma unroll
                for (int ot = 0; ot < 4; ++ot)
                    Bn[k3][ot] =
                        *(const short8*)(wtp + ((((cc + 1) * 3 + k3) * 4 + ot) * 64 + lane) * 8);
        }
        auto& Bc = (cc & 1) ? B1 : B0;
#pragma unroll
        for (int k3 = 0; k3 < 3; ++k3) {
            const int ks = cc * 3 + k3;
            const int tap = ks >> 1;
            const int c0 = (ks & 1) * 32 + c0g;
            short8 Af[4];
#pragma unroll
            for (int mf = 0; mf < 4; ++mf) {
                int st = st0 + mf * 16 + tap * 25;
                Af[mf] = *(const short8*)&ytile[(st * 64 + c0) ^ ((st & 7) << 3)];
            }
#pragma unroll
            for (int mf = 0; mf < 4; ++mf)
#pragma unroll
                for (int ot = 0; ot < 4; ++ot)
                    acc[mf][ot] = MFMA16(Af[mf], Bc[k3][ot], acc[mf][ot]);
        }
    }

    // epilogue: BN2 + residual(x fp32, contiguous) + relu -> out
    const size_t obase = (size_t)n * 64 * 25600;
#pragma unroll
    for (int mf = 0; mf < 4; ++mf)
#pragma unroll
        for (int ot = 0; ot < 4; ++ot) {
            int o = ot * 16 + (lane & 15);
            size_t rowb = obase + (size_t)o * 25600 +
                          (size_t)(col0 + wv * 64 + mf * 16 + (lane >> 4) * 4);
            f32x4 xv = *(const f32x4*)(x + rowb);
            f32x4 r;
#pragma unroll
            for (int e = 0; e < 4; ++e)
                r[e] = fmaxf(fmaf(acc[mf][ot][e], sa[ot], sb[ot]) + xv[e], 0.f);
            *(f32x4*)(out + rowb) = r;
        }
}

extern "C" void kernel_launch(void* const* d_in, const int* in_sizes, int n_in,
                              void* d_out, int out_size, void* d_ws, size_t ws_size,
                              hipStream_t stream) {
    const float* x = (const float*)d_in[0];
    const float* A = (const float*)d_in[1];
    const float* attn = (const float*)d_in[2];
    const float* wg = (const float*)d_in[3];
    const float* bg = (const float*)d_in[4];
    const float* g1 = (const float*)d_in[5];
    const float* b1 = (const float*)d_in[6];
    const float* m1 = (const float*)d_in[7];
    const float* v1 = (const float*)d_in[8];
    const float* wt = (const float*)d_in[9];
    const float* bt = (const float*)d_in[10];
    const float* g2 = (const float*)d_in[11];
    const float* b2 = (const float*)d_in[12];
    const float* m2 = (const float*)d_in[13];
    const float* v2 = (const float*)d_in[14];
    char* ws = (char*)d_ws;
    float* out = (float*)d_out;

    hipLaunchKernelGGL(prep_kernel, dim3(1), dim3(512), 0, stream, A, attn, wg, bg, g1, b1, m1,
                       v1, wt, bt, g2, b2, m2, v2, ws);
    hipLaunchKernelGGL(gcn_kernel, dim3(64, 32), dim3(512), 0, stream, x, ws);
    hipLaunchKernelGGL(tcn_kernel, dim3(50, 32), dim3(512), 0, stream, x, ws, out);
}